// Round 1
// baseline (642.777 us; speedup 1.0000x reference)
//
#include <hip/hip_runtime.h>

// ---------------------------------------------------------------------------
// AWQ int4 dequant GEMM: out = x @ dequant(qweight, scales, qzeros) + bias
// M=4096, K=4096, N=11008, group=128
// Plan: ws = [ A bf16 [M][K] | Bt bf16 [N][K] ]; 3 kernels on stream:
//   1) convert_x: fp32->bf16
//   2) dequant_awq: unpack int4 (AWQ nibble order), (q-z)*s -> bf16, transpose to [N][K]
//   3) gemm_bf16: 128x128x32 tile, mfma_f32_16x16x32_bf16, global_load_lds staging,
//      double-buffered LDS, bias fused in epilogue.
// ---------------------------------------------------------------------------

typedef __bf16 bf16x8 __attribute__((ext_vector_type(8)));
typedef float f32x4 __attribute__((ext_vector_type(4)));
typedef unsigned short ushort8 __attribute__((ext_vector_type(8)));

__device__ __forceinline__ unsigned short f2bf(float f) {
  // round-to-nearest-even fp32 -> bf16 (values are finite here)
  unsigned int u = __builtin_bit_cast(unsigned int, f);
  u += 0x7FFFu + ((u >> 16) & 1u);
  return (unsigned short)(u >> 16);
}

__device__ __forceinline__ void gload16(const void* g, void* l) {
  // async global->LDS, 16B per lane; LDS dest = wave-uniform base + lane*16
  __builtin_amdgcn_global_load_lds(
      (const __attribute__((address_space(1))) unsigned int*)g,
      (__attribute__((address_space(3))) unsigned int*)l, 16, 0, 0);
}

// ---------------------------------------------------------------------------
// Kernel 1: x fp32 -> A bf16 (vectorized 8 elems/thread, grid-stride)
// ---------------------------------------------------------------------------
__global__ __launch_bounds__(256) void convert_x(const float* __restrict__ x,
                                                 unsigned short* __restrict__ A,
                                                 long long n8) {
  for (long long idx = (long long)blockIdx.x * 256 + threadIdx.x; idx < n8;
       idx += (long long)gridDim.x * 256) {
    float4 u = ((const float4*)x)[2 * idx];
    float4 v = ((const float4*)x)[2 * idx + 1];
    ushort8 o;
    o[0] = f2bf(u.x); o[1] = f2bf(u.y); o[2] = f2bf(u.z); o[3] = f2bf(u.w);
    o[4] = f2bf(v.x); o[5] = f2bf(v.y); o[6] = f2bf(v.z); o[7] = f2bf(v.w);
    ((ushort8*)A)[idx] = o;
  }
}

// ---------------------------------------------------------------------------
// Kernel 2: AWQ dequant + transpose -> Bt bf16 [N][K]
// Tile 64k x 64n per block (one group row per tile since 128 % 64 == 0).
// AWQ nibble order [0,4,1,5,2,6,3,7] -> shifts {0,16,4,20,8,24,12,28}.
// ---------------------------------------------------------------------------
__global__ __launch_bounds__(256) void dequant_awq(const int* __restrict__ qw,
                                                   const float* __restrict__ sc,
                                                   const int* __restrict__ qz,
                                                   unsigned short* __restrict__ Bt,
                                                   int K, int N) {
  const int n8w = N >> 3;
  const int tiles_n = N >> 6;
  const int tk = blockIdx.x / tiles_n;
  const int tn = blockIdx.x % tiles_n;
  const int k0 = tk << 6, n0 = tn << 6;
  const int g = k0 >> 7;  // group row (tile never straddles a group)
  __shared__ unsigned short tile[64][72];  // [k][n], pad 8 keeps 16B-aligned rows
  __shared__ float s_s[64];
  __shared__ float s_z[64];
  const int t = threadIdx.x;
  if (t < 64) {
    s_s[t] = sc[(size_t)g * N + n0 + t];
  } else if (t < 72) {
    const int j = t - 64;
    const int zq = qz[(size_t)g * n8w + (n0 >> 3) + j];
    s_z[j * 8 + 0] = (float)((zq >> 0) & 0xF);
    s_z[j * 8 + 1] = (float)((zq >> 16) & 0xF);
    s_z[j * 8 + 2] = (float)((zq >> 4) & 0xF);
    s_z[j * 8 + 3] = (float)((zq >> 20) & 0xF);
    s_z[j * 8 + 4] = (float)((zq >> 8) & 0xF);
    s_z[j * 8 + 5] = (float)((zq >> 24) & 0xF);
    s_z[j * 8 + 6] = (float)((zq >> 12) & 0xF);
    s_z[j * 8 + 7] = (float)((zq >> 28) & 0xF);
  }
  __syncthreads();
#pragma unroll
  for (int r = 0; r < 2; ++r) {
    const int d = (r << 8) + t;  // 0..511
    const int kk = d >> 3, j = d & 7;
    const int q = qw[(size_t)(k0 + kk) * n8w + (n0 >> 3) + j];
    const int base = j << 3;
    ushort8 o;
    o[0] = f2bf(((float)((q >> 0) & 0xF) - s_z[base + 0]) * s_s[base + 0]);
    o[1] = f2bf(((float)((q >> 16) & 0xF) - s_z[base + 1]) * s_s[base + 1]);
    o[2] = f2bf(((float)((q >> 4) & 0xF) - s_z[base + 2]) * s_s[base + 2]);
    o[3] = f2bf(((float)((q >> 20) & 0xF) - s_z[base + 3]) * s_s[base + 3]);
    o[4] = f2bf(((float)((q >> 8) & 0xF) - s_z[base + 4]) * s_s[base + 4]);
    o[5] = f2bf(((float)((q >> 24) & 0xF) - s_z[base + 5]) * s_s[base + 5]);
    o[6] = f2bf(((float)((q >> 12) & 0xF) - s_z[base + 6]) * s_s[base + 6]);
    o[7] = f2bf(((float)((q >> 28) & 0xF) - s_z[base + 7]) * s_s[base + 7]);
    *(ushort8*)&tile[kk][base] = o;
  }
  __syncthreads();
#pragma unroll
  for (int r = 0; r < 2; ++r) {
    const int d = (r << 8) + t;
    const int nl = d >> 3, seg = d & 7;
    ushort8 o;
#pragma unroll
    for (int i = 0; i < 8; ++i) o[i] = tile[(seg << 3) + i][nl];
    *(ushort8*)&Bt[(size_t)(n0 + nl) * K + k0 + (seg << 3)] = o;
  }
}

// ---------------------------------------------------------------------------
// Kernel 3: bf16 GEMM, C = A @ Bt^T + bias.  A [M][K], Bt [N][K], C fp32 [M][N].
// 128x128 tile, BK=32, 4 waves (2x2), each wave 64x64 via 4x4 16x16 fragments.
// m97 structure: global_load_lds(16B) staging + double-buffered LDS.
// ---------------------------------------------------------------------------
#define BM 128
#define BN 128
#define BK 32

__global__ __launch_bounds__(256) void gemm_bf16(const unsigned short* __restrict__ A,
                                                 const unsigned short* __restrict__ Bt,
                                                 const float* __restrict__ bias,
                                                 float* __restrict__ C,
                                                 int M, int N, int K) {
  __shared__ unsigned short sm[2][8192];  // per buf: A tile [128][32] | B tile [128][32]
  const int tid = threadIdx.x;
  const int wave = tid >> 6;
  const int lane = tid & 63;
  const int ntn = N / BN;
  const int bm = blockIdx.x / ntn;
  const int bn = blockIdx.x % ntn;
  const int brow = bm * BM, bcol = bn * BN;

  // staging: thread t covers LDS shorts [t*8 .. t*8+7] of each 4096-short half-tile
  // = row (t>>2), k-chunk (t&3)*8 of a [128][32] row-major tile.
  const unsigned short* gA0 = A + (size_t)(brow + (tid >> 2)) * K + (tid & 3) * 8;
  const unsigned short* gA1 = gA0 + (size_t)64 * K;
  const unsigned short* gB0 = Bt + (size_t)(bcol + (tid >> 2)) * K + (tid & 3) * 8;
  const unsigned short* gB1 = gB0 + (size_t)64 * K;

  const int wm = wave >> 1, wn = wave & 1;
  const int aoff = (wm * 64 + (lane & 15)) * BK + (lane >> 4) * 8;
  const int boff = 4096 + (wn * 64 + (lane & 15)) * BK + (lane >> 4) * 8;

  f32x4 acc[4][4];
#pragma unroll
  for (int m = 0; m < 4; ++m)
#pragma unroll
    for (int n = 0; n < 4; ++n) acc[m][n] = (f32x4){0.f, 0.f, 0.f, 0.f};

  const int ldsbase = wave * 512;  // shorts; gload writes base + lane*16B

  auto stage = [&](int b, int kt) {
    const int k0 = kt * BK;
    gload16(gA0 + k0, &sm[b][0 + ldsbase]);
    gload16(gA1 + k0, &sm[b][2048 + ldsbase]);
    gload16(gB0 + k0, &sm[b][4096 + ldsbase]);
    gload16(gB1 + k0, &sm[b][6144 + ldsbase]);
  };

  const int nk = K / BK;
  stage(0, 0);
  __syncthreads();

  for (int kt = 0; kt < nk; ++kt) {
    const int cur = kt & 1;
    if (kt + 1 < nk) stage(cur ^ 1, kt + 1);
    bf16x8 a[4], b[4];
#pragma unroll
    for (int m = 0; m < 4; ++m)
      a[m] = *(const bf16x8*)&sm[cur][aoff + m * 16 * BK];
#pragma unroll
    for (int n = 0; n < 4; ++n)
      b[n] = *(const bf16x8*)&sm[cur][boff + n * 16 * BK];
#pragma unroll
    for (int m = 0; m < 4; ++m)
#pragma unroll
      for (int n = 0; n < 4; ++n)
        acc[m][n] = __builtin_amdgcn_mfma_f32_16x16x32_bf16(a[m], b[n], acc[m][n], 0, 0, 0);
    __syncthreads();
  }

  // epilogue: C/D layout col=lane&15, row=(lane>>4)*4+reg (m89-verified)
#pragma unroll
  for (int n = 0; n < 4; ++n) {
    const int col = bcol + wn * 64 + n * 16 + (lane & 15);
    const float bv = bias[col];
#pragma unroll
    for (int m = 0; m < 4; ++m) {
      const int row0 = brow + wm * 64 + m * 16 + ((lane >> 4) << 2);
#pragma unroll
      for (int q = 0; q < 4; ++q)
        C[(size_t)(row0 + q) * N + col] = acc[m][n][q] + bv;
    }
  }
}

// ---------------------------------------------------------------------------
extern "C" void kernel_launch(void* const* d_in, const int* in_sizes, int n_in,
                              void* d_out, int out_size, void* d_ws, size_t ws_size,
                              hipStream_t stream) {
  const float* x = (const float*)d_in[0];
  const int* qw = (const int*)d_in[1];
  const float* sc = (const float*)d_in[2];
  const int* qz = (const int*)d_in[3];
  const float* bias = (const float*)d_in[4];
  float* out = (float*)d_out;

  const int N = in_sizes[4];                                  // 11008
  const int K = (int)(((long long)in_sizes[1] * 8) / N);      // 4096
  const int M = in_sizes[0] / K;                              // 4096

  const size_t a_elems = (size_t)M * K;
  const size_t b_elems = (size_t)N * K;
  const size_t need = (a_elems + b_elems) * sizeof(unsigned short);
  if (ws_size < need) return;  // fail validation cleanly rather than corrupt memory

  unsigned short* A = (unsigned short*)d_ws;
  unsigned short* Bt = A + a_elems;

  convert_x<<<2048, 256, 0, stream>>>(x, A, (long long)(a_elems / 8));
  dequant_awq<<<(K / 64) * (N / 64), 256, 0, stream>>>(qw, sc, qz, Bt, K, N);
  gemm_bf16<<<(M / BM) * (N / BN), 256, 0, stream>>>(A, Bt, bias, out, M, N, K);
}

// Round 2
// 409.723 us; speedup vs baseline: 1.5688x; 1.5688x over previous
//
#include <hip/hip_runtime.h>

// ---------------------------------------------------------------------------
// AWQ int4 dequant GEMM: out = x @ dequant(qweight, scales, qzeros) + bias
// M=4096, K=4096, N=11008, group=128
//   1) convert_x: fp32->bf16 A[M][K]
//   2) dequant_awq: int4 -> bf16 Bt[N][K]
//   3) gemm_bf16: 256x256 8-phase template (T1+T2+T3+T4+T5), BK=64, 512 thr,
//      counted vmcnt(6), XOR-swizzled LDS (pre-swizzled global source),
//      bias fused in epilogue.
// ---------------------------------------------------------------------------

typedef __bf16 bf16x8 __attribute__((ext_vector_type(8)));
typedef float f32x4 __attribute__((ext_vector_type(4)));
typedef unsigned short ushort8 __attribute__((ext_vector_type(8)));

__device__ __forceinline__ unsigned short f2bf(float f) {
  unsigned int u = __builtin_bit_cast(unsigned int, f);
  u += 0x7FFFu + ((u >> 16) & 1u);
  return (unsigned short)(u >> 16);
}

__device__ __forceinline__ void gload16(const void* g, void* l) {
  __builtin_amdgcn_global_load_lds(
      (const __attribute__((address_space(1))) unsigned int*)g,
      (__attribute__((address_space(3))) unsigned int*)l, 16, 0, 0);
}

// ---------------------------------------------------------------------------
// Kernel 1: x fp32 -> A bf16
// ---------------------------------------------------------------------------
__global__ __launch_bounds__(256) void convert_x(const float* __restrict__ x,
                                                 unsigned short* __restrict__ A,
                                                 long long n8) {
  for (long long idx = (long long)blockIdx.x * 256 + threadIdx.x; idx < n8;
       idx += (long long)gridDim.x * 256) {
    float4 u = ((const float4*)x)[2 * idx];
    float4 v = ((const float4*)x)[2 * idx + 1];
    ushort8 o;
    o[0] = f2bf(u.x); o[1] = f2bf(u.y); o[2] = f2bf(u.z); o[3] = f2bf(u.w);
    o[4] = f2bf(v.x); o[5] = f2bf(v.y); o[6] = f2bf(v.z); o[7] = f2bf(v.w);
    ((ushort8*)A)[idx] = o;
  }
}

// ---------------------------------------------------------------------------
// Kernel 2: AWQ dequant + transpose -> Bt bf16 [N][K]
// ---------------------------------------------------------------------------
__global__ __launch_bounds__(256) void dequant_awq(const int* __restrict__ qw,
                                                   const float* __restrict__ sc,
                                                   const int* __restrict__ qz,
                                                   unsigned short* __restrict__ Bt,
                                                   int K, int N) {
  const int n8w = N >> 3;
  const int tiles_n = N >> 6;
  const int tk = blockIdx.x / tiles_n;
  const int tn = blockIdx.x % tiles_n;
  const int k0 = tk << 6, n0 = tn << 6;
  const int g = k0 >> 7;
  __shared__ unsigned short tile[64][72];
  __shared__ float s_s[64];
  __shared__ float s_z[64];
  const int t = threadIdx.x;
  if (t < 64) {
    s_s[t] = sc[(size_t)g * N + n0 + t];
  } else if (t < 72) {
    const int j = t - 64;
    const int zq = qz[(size_t)g * n8w + (n0 >> 3) + j];
    s_z[j * 8 + 0] = (float)((zq >> 0) & 0xF);
    s_z[j * 8 + 1] = (float)((zq >> 16) & 0xF);
    s_z[j * 8 + 2] = (float)((zq >> 4) & 0xF);
    s_z[j * 8 + 3] = (float)((zq >> 20) & 0xF);
    s_z[j * 8 + 4] = (float)((zq >> 8) & 0xF);
    s_z[j * 8 + 5] = (float)((zq >> 24) & 0xF);
    s_z[j * 8 + 6] = (float)((zq >> 12) & 0xF);
    s_z[j * 8 + 7] = (float)((zq >> 28) & 0xF);
  }
  __syncthreads();
#pragma unroll
  for (int r = 0; r < 2; ++r) {
    const int d = (r << 8) + t;
    const int kk = d >> 3, j = d & 7;
    const int q = qw[(size_t)(k0 + kk) * n8w + (n0 >> 3) + j];
    const int base = j << 3;
    ushort8 o;
    o[0] = f2bf(((float)((q >> 0) & 0xF) - s_z[base + 0]) * s_s[base + 0]);
    o[1] = f2bf(((float)((q >> 16) & 0xF) - s_z[base + 1]) * s_s[base + 1]);
    o[2] = f2bf(((float)((q >> 4) & 0xF) - s_z[base + 2]) * s_s[base + 2]);
    o[3] = f2bf(((float)((q >> 20) & 0xF) - s_z[base + 3]) * s_s[base + 3]);
    o[4] = f2bf(((float)((q >> 8) & 0xF) - s_z[base + 4]) * s_s[base + 4]);
    o[5] = f2bf(((float)((q >> 24) & 0xF) - s_z[base + 5]) * s_s[base + 5]);
    o[6] = f2bf(((float)((q >> 12) & 0xF) - s_z[base + 6]) * s_s[base + 6]);
    o[7] = f2bf(((float)((q >> 28) & 0xF) - s_z[base + 7]) * s_s[base + 7]);
    *(ushort8*)&tile[kk][base] = o;
  }
  __syncthreads();
#pragma unroll
  for (int r = 0; r < 2; ++r) {
    const int d = (r << 8) + t;
    const int nl = d >> 3, seg = d & 7;
    ushort8 o;
#pragma unroll
    for (int i = 0; i < 8; ++i) o[i] = tile[(seg << 3) + i][nl];
    *(ushort8*)&Bt[(size_t)(n0 + nl) * K + k0 + (seg << 3)] = o;
  }
}

// ---------------------------------------------------------------------------
// Kernel 3: 256x256 8-phase bf16 GEMM.  A [M][K], Bt [N][K], C fp32 [M][N].
// 8 waves (2M x 4N), per-wave 128x64 output = acc[8][4] f32x4.
// LDS: 2 bufs x (A[256][64] + B[256][64]) = 128 KiB, XOR-swizzled content
// (k_shorts ^= (row&7)<<3) via pre-swizzled GLOBAL source (linear LDS dest).
// Half-tiles h: 0=A rows0-127, 1=A rows128-255, 2=B rows0-127, 3=B rows128-255.
// Stage slot at global phase p stages half index p+7 (prologue staged 0..6).
// vmcnt(6) once per K-tile (phase 4) => tile t+1 fully landed before use.
// ---------------------------------------------------------------------------
#define BM 256
#define BN 256
#define BK 64

__global__ __launch_bounds__(512, 2) void gemm_bf16(const unsigned short* __restrict__ A,
                                                    const unsigned short* __restrict__ Bt,
                                                    const float* __restrict__ bias,
                                                    float* __restrict__ C,
                                                    int M, int N, int K) {
  __shared__ __align__(16) unsigned short sm[2][32768];
  const int tid = threadIdx.x;
  const int w = tid >> 6, lane = tid & 63;
  const int wm = w >> 2, wn = w & 3;

  // T1: XCD-aware swizzle (grid = 688, 688 % 8 == 0 -> exact)
  const int nbn = N / BN;
  const int cpx = gridDim.x >> 3;
  const int g = (blockIdx.x & 7) * cpx + (blockIdx.x >> 3);
  const int bm = g / nbn, bn = g % nbn;
  const int brow = bm * BM, bcol = bn * BN;

  // staging: thread covers row srow(+i*64+(h&1)*128), pre-swizzled k chunk
  const int srow = tid >> 3;                                // 0..63
  const int kswz = ((tid & 7) ^ (srow & 7)) << 3;           // shorts
  const unsigned short* pA = A + (size_t)(brow + srow) * K + kswz;
  const unsigned short* pB = Bt + (size_t)(bcol + srow) * K + kswz;

  // frag reads: row R = base + (lane&15); col bytes = (ks*64+q*16) ^ ((R&7)<<4)
  const int aBase = (wm * 128 + (lane & 15)) * 64;          // shorts
  const int bBase = 16384 + (wn * 64 + (lane & 15)) * 64;
  const int col0 = (((lane >> 4) * 16) ^ ((lane & 7) << 4)) >> 1;        // shorts
  const int col1 = ((64 + (lane >> 4) * 16) ^ ((lane & 7) << 4)) >> 1;

  const int NKt = K / BK;
  const int nhalf = NKt * 4;

  f32x4 acc[8][4];
#pragma unroll
  for (int m = 0; m < 8; ++m)
#pragma unroll
    for (int n = 0; n < 4; ++n) acc[m][n] = (f32x4){0.f, 0.f, 0.f, 0.f};

  auto stage_half = [&](int s) {
    if (s < nhalf) {
      const int kt = s >> 2, h = s & 3;
      const unsigned short* src =
          ((h & 2) ? pB : pA) + (size_t)((h & 1) * 128) * K + (size_t)kt * BK;
      unsigned short* dst = &sm[kt & 1][(h << 13) + (w << 9)];
      gload16(src, dst);
      gload16(src + (size_t)64 * K, dst + 4096);
    }
  };

  // prologue: tile0 (4 halves) + tile1 h0-2; wait tile0 landed
  for (int s = 0; s < 7; ++s) stage_half(s);
  asm volatile("s_waitcnt vmcnt(6)" ::: "memory");
  __builtin_amdgcn_s_barrier();

  for (int t = 0; t < NKt; ++t) {
    const unsigned short* bp = sm[t & 1];
    const int sb = 4 * t + 7;
    bf16x8 a0[4][2], a1[4][2], bb0[2][2], bb1[2][2];

    // ---- phase 1: read a0 (m0-3) + bb0 (n0-1); stage; MFMA q0 ----
#pragma unroll
    for (int m = 0; m < 4; ++m) {
      a0[m][0] = *(const bf16x8*)(bp + aBase + m * 1024 + col0);
      a0[m][1] = *(const bf16x8*)(bp + aBase + m * 1024 + col1);
    }
#pragma unroll
    for (int n = 0; n < 2; ++n) {
      bb0[n][0] = *(const bf16x8*)(bp + bBase + n * 1024 + col0);
      bb0[n][1] = *(const bf16x8*)(bp + bBase + n * 1024 + col1);
    }
    stage_half(sb + 0);
    __builtin_amdgcn_s_barrier();
    asm volatile("s_waitcnt lgkmcnt(0)" ::: "memory");
    __builtin_amdgcn_sched_barrier(0);
    __builtin_amdgcn_s_setprio(1);
#pragma unroll
    for (int m = 0; m < 4; ++m)
#pragma unroll
      for (int n = 0; n < 2; ++n) {
        acc[m][n] = __builtin_amdgcn_mfma_f32_16x16x32_bf16(a0[m][0], bb0[n][0], acc[m][n], 0, 0, 0);
        acc[m][n] = __builtin_amdgcn_mfma_f32_16x16x32_bf16(a0[m][1], bb0[n][1], acc[m][n], 0, 0, 0);
      }
    __builtin_amdgcn_s_setprio(0);
    __builtin_amdgcn_s_barrier();

    // ---- phase 2: read a1 (m4-7); stage; MFMA q1 ----
#pragma unroll
    for (int m = 0; m < 4; ++m) {
      a1[m][0] = *(const bf16x8*)(bp + aBase + 4096 + m * 1024 + col0);
      a1[m][1] = *(const bf16x8*)(bp + aBase + 4096 + m * 1024 + col1);
    }
    stage_half(sb + 1);
    __builtin_amdgcn_s_barrier();
    asm volatile("s_waitcnt lgkmcnt(0)" ::: "memory");
    __builtin_amdgcn_sched_barrier(0);
    __builtin_amdgcn_s_setprio(1);
#pragma unroll
    for (int m = 0; m < 4; ++m)
#pragma unroll
      for (int n = 0; n < 2; ++n) {
        acc[4 + m][n] = __builtin_amdgcn_mfma_f32_16x16x32_bf16(a1[m][0], bb0[n][0], acc[4 + m][n], 0, 0, 0);
        acc[4 + m][n] = __builtin_amdgcn_mfma_f32_16x16x32_bf16(a1[m][1], bb0[n][1], acc[4 + m][n], 0, 0, 0);
      }
    __builtin_amdgcn_s_setprio(0);
    __builtin_amdgcn_s_barrier();

    // ---- phase 3: read bb1 (n2-3); stage; MFMA q2 (reuses a0) ----
#pragma unroll
    for (int n = 0; n < 2; ++n) {
      bb1[n][0] = *(const bf16x8*)(bp + bBase + (n + 2) * 1024 + col0);
      bb1[n][1] = *(const bf16x8*)(bp + bBase + (n + 2) * 1024 + col1);
    }
    stage_half(sb + 2);
    __builtin_amdgcn_s_barrier();
    asm volatile("s_waitcnt lgkmcnt(0)" ::: "memory");
    __builtin_amdgcn_sched_barrier(0);
    __builtin_amdgcn_s_setprio(1);
#pragma unroll
    for (int m = 0; m < 4; ++m)
#pragma unroll
      for (int n = 0; n < 2; ++n) {
        acc[m][2 + n] = __builtin_amdgcn_mfma_f32_16x16x32_bf16(a0[m][0], bb1[n][0], acc[m][2 + n], 0, 0, 0);
        acc[m][2 + n] = __builtin_amdgcn_mfma_f32_16x16x32_bf16(a0[m][1], bb1[n][1], acc[m][2 + n], 0, 0, 0);
      }
    __builtin_amdgcn_s_setprio(0);
    __builtin_amdgcn_s_barrier();

    // ---- phase 4: stage; counted vmcnt; MFMA q3 (reuses a1, bb1) ----
    stage_half(sb + 3);
    if (t < NKt - 2) {
      asm volatile("s_waitcnt vmcnt(6)" ::: "memory");
    } else {
      asm volatile("s_waitcnt vmcnt(0)" ::: "memory");
    }
    __builtin_amdgcn_s_barrier();
    __builtin_amdgcn_s_setprio(1);
#pragma unroll
    for (int m = 0; m < 4; ++m)
#pragma unroll
      for (int n = 0; n < 2; ++n) {
        acc[4 + m][2 + n] = __builtin_amdgcn_mfma_f32_16x16x32_bf16(a1[m][0], bb1[n][0], acc[4 + m][2 + n], 0, 0, 0);
        acc[4 + m][2 + n] = __builtin_amdgcn_mfma_f32_16x16x32_bf16(a1[m][1], bb1[n][1], acc[4 + m][2 + n], 0, 0, 0);
      }
    __builtin_amdgcn_s_setprio(0);
    __builtin_amdgcn_s_barrier();
  }

  // epilogue: C/D layout col=lane&15, row=(lane>>4)*4+reg
#pragma unroll
  for (int n = 0; n < 4; ++n) {
    const int col = bcol + wn * 64 + n * 16 + (lane & 15);
    const float bv = bias[col];
#pragma unroll
    for (int m = 0; m < 8; ++m) {
      const int row0 = brow + wm * 128 + m * 16 + ((lane >> 4) << 2);
#pragma unroll
      for (int q = 0; q < 4; ++q)
        C[(size_t)(row0 + q) * N + col] = acc[m][n][q] + bv;
    }
  }
}

// ---------------------------------------------------------------------------
extern "C" void kernel_launch(void* const* d_in, const int* in_sizes, int n_in,
                              void* d_out, int out_size, void* d_ws, size_t ws_size,
                              hipStream_t stream) {
  const float* x = (const float*)d_in[0];
  const int* qw = (const int*)d_in[1];
  const float* sc = (const float*)d_in[2];
  const int* qz = (const int*)d_in[3];
  const float* bias = (const float*)d_in[4];
  float* out = (float*)d_out;

  const int N = in_sizes[4];                              // 11008
  const int K = (int)(((long long)in_sizes[1] * 8) / N);  // 4096
  const int M = in_sizes[0] / K;                          // 4096

  const size_t a_elems = (size_t)M * K;
  const size_t b_elems = (size_t)N * K;
  const size_t need = (a_elems + b_elems) * sizeof(unsigned short);
  if (ws_size < need) return;

  unsigned short* A = (unsigned short*)d_ws;
  unsigned short* Bt = A + a_elems;

  convert_x<<<2048, 256, 0, stream>>>(x, A, (long long)(a_elems / 8));
  dequant_awq<<<(K / 64) * (N / 64), 256, 0, stream>>>(qw, sc, qz, Bt, K, N);
  gemm_bf16<<<(M / BM) * (N / BN), 512, 0, stream>>>(A, Bt, bias, out, M, N, K);
}

// Round 3
// 408.909 us; speedup vs baseline: 1.5719x; 1.0020x over previous
//
#include <hip/hip_runtime.h>

// ---------------------------------------------------------------------------
// AWQ int4 dequant GEMM: out = x @ dequant(qweight, scales, qzeros) + bias
// M=4096, K=4096, N=11008, group=128
//   1) convert_x: fp32->bf16 A[M][K]
//   2) dequant_awq: int4 -> bf16 Bt[N][K]
//   3) gemm_bf16: 256x256 8-phase template (T1+T2+T3+T4+T5), BK=64, 512 thr,
//      counted vmcnt(6), XOR-swizzled LDS (pre-swizzled global source),
//      k-OUTER MFMA order (no dependent back-to-back MFMA), bias fused.
// ---------------------------------------------------------------------------

typedef __bf16 bf16x8 __attribute__((ext_vector_type(8)));
typedef float f32x4 __attribute__((ext_vector_type(4)));
typedef unsigned short ushort8 __attribute__((ext_vector_type(8)));

__device__ __forceinline__ unsigned short f2bf(float f) {
  unsigned int u = __builtin_bit_cast(unsigned int, f);
  u += 0x7FFFu + ((u >> 16) & 1u);
  return (unsigned short)(u >> 16);
}

__device__ __forceinline__ void gload16(const void* g, void* l) {
  __builtin_amdgcn_global_load_lds(
      (const __attribute__((address_space(1))) unsigned int*)g,
      (__attribute__((address_space(3))) unsigned int*)l, 16, 0, 0);
}

// ---------------------------------------------------------------------------
// Kernel 1: x fp32 -> A bf16
// ---------------------------------------------------------------------------
__global__ __launch_bounds__(256) void convert_x(const float* __restrict__ x,
                                                 unsigned short* __restrict__ A,
                                                 long long n8) {
  for (long long idx = (long long)blockIdx.x * 256 + threadIdx.x; idx < n8;
       idx += (long long)gridDim.x * 256) {
    float4 u = ((const float4*)x)[2 * idx];
    float4 v = ((const float4*)x)[2 * idx + 1];
    ushort8 o;
    o[0] = f2bf(u.x); o[1] = f2bf(u.y); o[2] = f2bf(u.z); o[3] = f2bf(u.w);
    o[4] = f2bf(v.x); o[5] = f2bf(v.y); o[6] = f2bf(v.z); o[7] = f2bf(v.w);
    ((ushort8*)A)[idx] = o;
  }
}

// ---------------------------------------------------------------------------
// Kernel 2: AWQ dequant + transpose -> Bt bf16 [N][K]
// ---------------------------------------------------------------------------
__global__ __launch_bounds__(256) void dequant_awq(const int* __restrict__ qw,
                                                   const float* __restrict__ sc,
                                                   const int* __restrict__ qz,
                                                   unsigned short* __restrict__ Bt,
                                                   int K, int N) {
  const int n8w = N >> 3;
  const int tiles_n = N >> 6;
  const int tk = blockIdx.x / tiles_n;
  const int tn = blockIdx.x % tiles_n;
  const int k0 = tk << 6, n0 = tn << 6;
  const int g = k0 >> 7;
  __shared__ unsigned short tile[64][72];
  __shared__ float s_s[64];
  __shared__ float s_z[64];
  const int t = threadIdx.x;
  if (t < 64) {
    s_s[t] = sc[(size_t)g * N + n0 + t];
  } else if (t < 72) {
    const int j = t - 64;
    const int zq = qz[(size_t)g * n8w + (n0 >> 3) + j];
    s_z[j * 8 + 0] = (float)((zq >> 0) & 0xF);
    s_z[j * 8 + 1] = (float)((zq >> 16) & 0xF);
    s_z[j * 8 + 2] = (float)((zq >> 4) & 0xF);
    s_z[j * 8 + 3] = (float)((zq >> 20) & 0xF);
    s_z[j * 8 + 4] = (float)((zq >> 8) & 0xF);
    s_z[j * 8 + 5] = (float)((zq >> 24) & 0xF);
    s_z[j * 8 + 6] = (float)((zq >> 12) & 0xF);
    s_z[j * 8 + 7] = (float)((zq >> 28) & 0xF);
  }
  __syncthreads();
#pragma unroll
  for (int r = 0; r < 2; ++r) {
    const int d = (r << 8) + t;
    const int kk = d >> 3, j = d & 7;
    const int q = qw[(size_t)(k0 + kk) * n8w + (n0 >> 3) + j];
    const int base = j << 3;
    ushort8 o;
    o[0] = f2bf(((float)((q >> 0) & 0xF) - s_z[base + 0]) * s_s[base + 0]);
    o[1] = f2bf(((float)((q >> 16) & 0xF) - s_z[base + 1]) * s_s[base + 1]);
    o[2] = f2bf(((float)((q >> 4) & 0xF) - s_z[base + 2]) * s_s[base + 2]);
    o[3] = f2bf(((float)((q >> 20) & 0xF) - s_z[base + 3]) * s_s[base + 3]);
    o[4] = f2bf(((float)((q >> 8) & 0xF) - s_z[base + 4]) * s_s[base + 4]);
    o[5] = f2bf(((float)((q >> 24) & 0xF) - s_z[base + 5]) * s_s[base + 5]);
    o[6] = f2bf(((float)((q >> 12) & 0xF) - s_z[base + 6]) * s_s[base + 6]);
    o[7] = f2bf(((float)((q >> 28) & 0xF) - s_z[base + 7]) * s_s[base + 7]);
    *(ushort8*)&tile[kk][base] = o;
  }
  __syncthreads();
#pragma unroll
  for (int r = 0; r < 2; ++r) {
    const int d = (r << 8) + t;
    const int nl = d >> 3, seg = d & 7;
    ushort8 o;
#pragma unroll
    for (int i = 0; i < 8; ++i) o[i] = tile[(seg << 3) + i][nl];
    *(ushort8*)&Bt[(size_t)(n0 + nl) * K + k0 + (seg << 3)] = o;
  }
}

// ---------------------------------------------------------------------------
// Kernel 3: 256x256 8-phase bf16 GEMM.  A [M][K], Bt [N][K], C fp32 [M][N].
// 8 waves (2M x 4N), per-wave 128x64 output = acc[8][4] f32x4.
// LDS: 2 bufs x (A[256][64] + B[256][64]) = 128 KiB, XOR-swizzled content
// (k_shorts ^= (row&7)<<3) via pre-swizzled GLOBAL source (linear LDS dest).
// MFMA clusters are k-OUTERMOST: dependent acc reuses are 8 instrs apart.
// ---------------------------------------------------------------------------
#define BM 256
#define BN 256
#define BK 64

__global__ __launch_bounds__(512, 2) void gemm_bf16(const unsigned short* __restrict__ A,
                                                    const unsigned short* __restrict__ Bt,
                                                    const float* __restrict__ bias,
                                                    float* __restrict__ C,
                                                    int M, int N, int K) {
  __shared__ __align__(16) unsigned short sm[2][32768];
  const int tid = threadIdx.x;
  const int w = tid >> 6, lane = tid & 63;
  const int wm = w >> 2, wn = w & 3;

  // T1: XCD-aware swizzle (grid = 688, 688 % 8 == 0 -> exact)
  const int nbn = N / BN;
  const int cpx = gridDim.x >> 3;
  const int g = (blockIdx.x & 7) * cpx + (blockIdx.x >> 3);
  const int bm = g / nbn, bn = g % nbn;
  const int brow = bm * BM, bcol = bn * BN;

  // staging: thread covers row srow(+i*64+(h&1)*128), pre-swizzled k chunk
  const int srow = tid >> 3;                                // 0..63
  const int kswz = ((tid & 7) ^ (srow & 7)) << 3;           // shorts
  const unsigned short* pA = A + (size_t)(brow + srow) * K + kswz;
  const unsigned short* pB = Bt + (size_t)(bcol + srow) * K + kswz;

  // frag reads: row R = base + (lane&15); col bytes = (ks*64+q*16) ^ ((R&7)<<4)
  const int aBase = (wm * 128 + (lane & 15)) * 64;          // shorts
  const int bBase = 16384 + (wn * 64 + (lane & 15)) * 64;
  const int col0 = (((lane >> 4) * 16) ^ ((lane & 7) << 4)) >> 1;        // shorts
  const int col1 = ((64 + (lane >> 4) * 16) ^ ((lane & 7) << 4)) >> 1;

  const int NKt = K / BK;
  const int nhalf = NKt * 4;

  f32x4 acc[8][4];
#pragma unroll
  for (int m = 0; m < 8; ++m)
#pragma unroll
    for (int n = 0; n < 4; ++n) acc[m][n] = (f32x4){0.f, 0.f, 0.f, 0.f};

  auto stage_half = [&](int s) {
    if (s < nhalf) {
      const int kt = s >> 2, h = s & 3;
      const unsigned short* src =
          ((h & 2) ? pB : pA) + (size_t)((h & 1) * 128) * K + (size_t)kt * BK;
      unsigned short* dst = &sm[kt & 1][(h << 13) + (w << 9)];
      gload16(src, dst);
      gload16(src + (size_t)64 * K, dst + 4096);
    }
  };

  // prologue: tile0 (4 halves) + tile1 h0-2; wait tile0 landed
  for (int s = 0; s < 7; ++s) stage_half(s);
  asm volatile("s_waitcnt vmcnt(6)" ::: "memory");
  __builtin_amdgcn_s_barrier();

  for (int t = 0; t < NKt; ++t) {
    const unsigned short* bp = sm[t & 1];
    const int sb = 4 * t + 7;
    bf16x8 a0[4][2], a1[4][2], bb0[2][2], bb1[2][2];

    // ---- phase 1: read a0 (m0-3) + bb0 (n0-1); stage; MFMA q0 ----
#pragma unroll
    for (int m = 0; m < 4; ++m) {
      a0[m][0] = *(const bf16x8*)(bp + aBase + m * 1024 + col0);
      a0[m][1] = *(const bf16x8*)(bp + aBase + m * 1024 + col1);
    }
#pragma unroll
    for (int n = 0; n < 2; ++n) {
      bb0[n][0] = *(const bf16x8*)(bp + bBase + n * 1024 + col0);
      bb0[n][1] = *(const bf16x8*)(bp + bBase + n * 1024 + col1);
    }
    stage_half(sb + 0);
    __builtin_amdgcn_s_barrier();
    asm volatile("s_waitcnt lgkmcnt(0)" ::: "memory");
    __builtin_amdgcn_sched_barrier(0);
    __builtin_amdgcn_s_setprio(1);
#pragma unroll
    for (int kk = 0; kk < 2; ++kk)
#pragma unroll
      for (int m = 0; m < 4; ++m)
#pragma unroll
        for (int n = 0; n < 2; ++n)
          acc[m][n] = __builtin_amdgcn_mfma_f32_16x16x32_bf16(a0[m][kk], bb0[n][kk], acc[m][n], 0, 0, 0);
    __builtin_amdgcn_s_setprio(0);
    __builtin_amdgcn_s_barrier();

    // ---- phase 2: read a1 (m4-7); stage; MFMA q1 ----
#pragma unroll
    for (int m = 0; m < 4; ++m) {
      a1[m][0] = *(const bf16x8*)(bp + aBase + 4096 + m * 1024 + col0);
      a1[m][1] = *(const bf16x8*)(bp + aBase + 4096 + m * 1024 + col1);
    }
    stage_half(sb + 1);
    __builtin_amdgcn_s_barrier();
    asm volatile("s_waitcnt lgkmcnt(0)" ::: "memory");
    __builtin_amdgcn_sched_barrier(0);
    __builtin_amdgcn_s_setprio(1);
#pragma unroll
    for (int kk = 0; kk < 2; ++kk)
#pragma unroll
      for (int m = 0; m < 4; ++m)
#pragma unroll
        for (int n = 0; n < 2; ++n)
          acc[4 + m][n] = __builtin_amdgcn_mfma_f32_16x16x32_bf16(a1[m][kk], bb0[n][kk], acc[4 + m][n], 0, 0, 0);
    __builtin_amdgcn_s_setprio(0);
    __builtin_amdgcn_s_barrier();

    // ---- phase 3: read bb1 (n2-3); stage; MFMA q2 (reuses a0) ----
#pragma unroll
    for (int n = 0; n < 2; ++n) {
      bb1[n][0] = *(const bf16x8*)(bp + bBase + (n + 2) * 1024 + col0);
      bb1[n][1] = *(const bf16x8*)(bp + bBase + (n + 2) * 1024 + col1);
    }
    stage_half(sb + 2);
    __builtin_amdgcn_s_barrier();
    asm volatile("s_waitcnt lgkmcnt(0)" ::: "memory");
    __builtin_amdgcn_sched_barrier(0);
    __builtin_amdgcn_s_setprio(1);
#pragma unroll
    for (int kk = 0; kk < 2; ++kk)
#pragma unroll
      for (int m = 0; m < 4; ++m)
#pragma unroll
        for (int n = 0; n < 2; ++n)
          acc[m][2 + n] = __builtin_amdgcn_mfma_f32_16x16x32_bf16(a0[m][kk], bb1[n][kk], acc[m][2 + n], 0, 0, 0);
    __builtin_amdgcn_s_setprio(0);
    __builtin_amdgcn_s_barrier();

    // ---- phase 4: stage; counted vmcnt; MFMA q3 (reuses a1, bb1) ----
    stage_half(sb + 3);
    if (t < NKt - 2) {
      asm volatile("s_waitcnt vmcnt(6)" ::: "memory");
    } else {
      asm volatile("s_waitcnt vmcnt(0)" ::: "memory");
    }
    __builtin_amdgcn_s_barrier();
    __builtin_amdgcn_s_setprio(1);
#pragma unroll
    for (int kk = 0; kk < 2; ++kk)
#pragma unroll
      for (int m = 0; m < 4; ++m)
#pragma unroll
        for (int n = 0; n < 2; ++n)
          acc[4 + m][2 + n] = __builtin_amdgcn_mfma_f32_16x16x32_bf16(a1[m][kk], bb1[n][kk], acc[4 + m][2 + n], 0, 0, 0);
    __builtin_amdgcn_s_setprio(0);
    __builtin_amdgcn_s_barrier();
  }

  // epilogue: C/D layout col=lane&15, row=(lane>>4)*4+reg
#pragma unroll
  for (int n = 0; n < 4; ++n) {
    const int col = bcol + wn * 64 + n * 16 + (lane & 15);
    const float bv = bias[col];
#pragma unroll
    for (int m = 0; m < 8; ++m) {
      const int row0 = brow + wm * 128 + m * 16 + ((lane >> 4) << 2);
#pragma unroll
      for (int q = 0; q < 4; ++q)
        C[(size_t)(row0 + q) * N + col] = acc[m][n][q] + bv;
    }
  }
}

// ---------------------------------------------------------------------------
extern "C" void kernel_launch(void* const* d_in, const int* in_sizes, int n_in,
                              void* d_out, int out_size, void* d_ws, size_t ws_size,
                              hipStream_t stream) {
  const float* x = (const float*)d_in[0];
  const int* qw = (const int*)d_in[1];
  const float* sc = (const float*)d_in[2];
  const int* qz = (const int*)d_in[3];
  const float* bias = (const float*)d_in[4];
  float* out = (float*)d_out;

  const int N = in_sizes[4];                              // 11008
  const int K = (int)(((long long)in_sizes[1] * 8) / N);  // 4096
  const int M = in_sizes[0] / K;                          // 4096

  const size_t a_elems = (size_t)M * K;
  const size_t b_elems = (size_t)N * K;
  const size_t need = (a_elems + b_elems) * sizeof(unsigned short);
  if (ws_size < need) return;

  unsigned short* A = (unsigned short*)d_ws;
  unsigned short* Bt = A + a_elems;

  convert_x<<<2048, 256, 0, stream>>>(x, A, (long long)(a_elems / 8));
  dequant_awq<<<(K / 64) * (N / 64), 256, 0, stream>>>(qw, sc, qz, Bt, K, N);
  gemm_bf16<<<(M / BM) * (N / BN), 512, 0, stream>>>(A, Bt, bias, out, M, N, K);
}